// Round 14
// baseline (151.910 us; speedup 1.0000x reference)
//
#include <hip/hip_runtime.h>
#include <math.h>

#define G    64
#define NPG  2048
#define NTOT (G * NPG)          // 131072
#define EPG  (NPG * 8)          // 16384 edges per graph (contiguous by construction)
#define NE   (NTOT * 8)         // 1048576
#define KSEL 410
#define NH   3
#define NC   20
#define HC   60
#define FCAP 24
#define KPAD 512
#define RP   12                 // padded row: h1[0..9], dinv@10, pad@11 (48 B)
#define CPG  4                  // dst-chunks per graph
#define NCK  (NPG / CPG)        // 512 nodes per chunk
#define CSCAP 5632              // chunk csr capacity (mean 4096, ~28 sigma headroom)

__device__ inline float leaky(float x) { return x >= 0.f ? x : 0.2f * x; }

__device__ inline int wave_incl_scan(int v) {
    int lane = threadIdx.x & 63;
#pragma unroll
    for (int d = 1; d < 64; d <<= 1) {
        int t = __shfl_up(v, d, 64);
        if (lane >= d) v += t;
    }
    return v;
}

// ---------------------------------------------------------------------------
// 1. Front-end: 4 blocks per graph (dst-chunked). Full-graph h1 + histogram in
//    LDS (redundant per chunk, keeps all gathers local); chunk scatter; chunk
//    GCN10 gather. ~125 KB LDS, 1024 thr.
// ---------------------------------------------------------------------------
__global__ __launch_bounds__(1024) void k_front(
    const float* __restrict__ x, const int* __restrict__ src, const int* __restrict__ dst,
    const float* __restrict__ W1, const float* __restrict__ b1, const float* __restrict__ Ws,
    float* __restrict__ x1g, float* __restrict__ hsg, float* __restrict__ dinvg,
    int* __restrict__ rowptrg, unsigned short* __restrict__ csrg)
{
    __shared__ __align__(16) float h1p[NPG * RP];   // 98304 B
    __shared__ int hist[NPG];                       // 8192
    __shared__ int rs[NPG];                         // 8192
    __shared__ unsigned short csrC[CSCAP];          // 11264
    __shared__ int wsumL[16];
    int tid = threadIdx.x, wid = tid >> 6;
    int g = blockIdx.x >> 2, ck = blockIdx.x & 3;
    int nbase = g * NPG, ebase = g * EPG;
    int nlo = ck * NCK, nhi = nlo + NCK;

    for (int i = tid; i < NPG; i += 1024) hist[i] = 0;
    for (int i = tid; i < NPG; i += 1024) {
        float xi[5];
#pragma unroll
        for (int k = 0; k < 5; k++) xi[k] = x[(size_t)(nbase + i) * 5 + k];
        float v[10];
#pragma unroll
        for (int j = 0; j < 10; j++) {
            float s = 0.f;
#pragma unroll
            for (int k = 0; k < 5; k++) s += xi[k] * W1[k * 10 + j];
            v[j] = s;
        }
        float4* row = (float4*)(h1p + i * RP);
        row[0] = make_float4(v[0], v[1], v[2], v[3]);
        row[1] = make_float4(v[4], v[5], v[6], v[7]);
        row[2] = make_float4(v[8], v[9], 0.f, 0.f);   // slot 10 = dinv (written below)
    }
    __syncthreads();
    for (int e = tid; e < EPG; e += 1024)
        atomicAdd(&hist[dst[ebase + e] - nbase], 1);
    __syncthreads();
    {   // exclusive scan (2 bins/thread, 16 wave partials); dinv -> slot 10; cursors
        int b2 = tid * 2;
        int v0 = hist[b2], v1 = hist[b2 + 1];
        int s = v0 + v1;
        int incl = wave_incl_scan(s);
        if ((tid & 63) == 63) wsumL[wid] = incl;
        __syncthreads();
        if (tid == 0) {
            int a = 0;
#pragma unroll
            for (int w = 0; w < 16; w++) { int t = wsumL[w]; wsumL[w] = a; a += t; }
        }
        __syncthreads();
        int base = wsumL[wid] + incl - s;
        rs[b2] = base;
        rs[b2 + 1] = base + v0;
        h1p[b2 * RP + 10] = rsqrtf((float)v0 + 1.0f);
        h1p[(b2 + 1) * RP + 10] = rsqrtf((float)v1 + 1.0f);
        hist[b2] = 0; hist[b2 + 1] = 0;
    }
    __syncthreads();
    int csbase = rs[nlo];
    int csend = (nhi == NPG) ? EPG : rs[nhi];
    if (tid < NCK) {
        int i = nlo + tid;
        rowptrg[nbase + i] = ebase + rs[i];
        dinvg[nbase + i] = h1p[i * RP + 10];
    }
    if (blockIdx.x == G * CPG - 1 && tid == 0) rowptrg[NTOT] = NE;  // sentinel
    // scatter this chunk's edges into LDS csr (positions rebased to csbase)
    for (int e = tid; e < EPG; e += 1024) {
        int ee = ebase + e;
        int dl = dst[ee] - nbase;
        if (dl >= nlo && dl < nhi) {
            int sl = src[ee] - nbase;
            int pos = rs[dl] - csbase + atomicAdd(&hist[dl], 1);
            if (pos < CSCAP) csrC[pos] = (unsigned short)sl;
        }
    }
    __syncthreads();
    {   // coalesced csr writeout
        int cnt = csend - csbase;
        for (int w = tid; w < cnt; w += 1024) csrg[ebase + csbase + w] = csrC[w];
    }
    // GCN10 gather for own 512 nodes (all reads from LDS)
    if (tid < NCK) {
        int i = nlo + tid;
        const float4* rowi = (const float4*)(h1p + i * RP);
        float4 s0 = rowi[0], s1 = rowi[1], s2 = rowi[2];
        float di = s2.z;
        float a0 = 0.f, a1 = 0.f, a2 = 0.f, a3 = 0.f, a4 = 0.f;
        float a5 = 0.f, a6 = 0.f, a7 = 0.f, a8 = 0.f, a9 = 0.f;
        int p0 = rs[i] - csbase;
        int p1 = ((i == nhi - 1) ? csend : rs[i + 1]) - csbase;
        for (int e = p0; e < p1; e++) {
            int s = csrC[e];
            const float4* rw = (const float4*)(h1p + s * RP);
            float4 r0 = rw[0], r1 = rw[1], r2 = rw[2];
            float dv = r2.z;
            a0 += r0.x * dv; a1 += r0.y * dv; a2 += r0.z * dv; a3 += r0.w * dv;
            a4 += r1.x * dv; a5 += r1.y * dv; a6 += r1.z * dv; a7 += r1.w * dv;
            a8 += r2.x * dv; a9 += r2.y * dv;
        }
        float d2 = di * di;
        float v[10];
        v[0] = a0 * di + s0.x * d2 + b1[0];
        v[1] = a1 * di + s0.y * d2 + b1[1];
        v[2] = a2 * di + s0.z * d2 + b1[2];
        v[3] = a3 * di + s0.w * d2 + b1[3];
        v[4] = a4 * di + s1.x * d2 + b1[4];
        v[5] = a5 * di + s1.y * d2 + b1[5];
        v[6] = a6 * di + s1.z * d2 + b1[6];
        v[7] = a7 * di + s1.w * d2 + b1[7];
        v[8] = a8 * di + s2.x * d2 + b1[8];
        v[9] = a9 * di + s2.y * d2 + b1[9];
        float dot = 0.f;
#pragma unroll
        for (int j = 0; j < 10; j++) dot += v[j] * Ws[j];
        float4* xr = (float4*)(x1g + (size_t)(nbase + i) * RP);
        xr[0] = make_float4(v[0], v[1], v[2], v[3]);
        xr[1] = make_float4(v[4], v[5], v[6], v[7]);
        xr[2] = make_float4(v[8], v[9], 0.f, 0.f);
        hsg[nbase + i] = dot;
    }
}

// ---------------------------------------------------------------------------
// 2. Scorer: 4 blocks per graph, 512 thr (1 node/thread). dinv/hs staged in
//    LDS; csr rows read (coalesced across adjacent threads) from global.
// ---------------------------------------------------------------------------
__global__ __launch_bounds__(512) void k_score(
    const float* __restrict__ hsg, const float* __restrict__ dinvg,
    const int* __restrict__ rowptrg, const unsigned short* __restrict__ csrg,
    const float* __restrict__ bs, float* __restrict__ scoreg)
{
    __shared__ float2 dh[NPG];    // 16 KB: (dinv, hs)
    int tid = threadIdx.x;
    int g = blockIdx.x >> 2, ck = blockIdx.x & 3;
    int nbase = g * NPG;
    for (int i = tid; i < NPG; i += 512)
        dh[i] = make_float2(dinvg[nbase + i], hsg[nbase + i]);
    __syncthreads();
    int i = ck * NCK + tid;
    float di = dh[i].x;
    int p0 = rowptrg[nbase + i], p1 = rowptrg[nbase + i + 1];
    float a = 0.f;
    for (int e = p0; e < p1; e++) {
        float2 t = dh[csrg[e]];
        a += t.x * t.y;
    }
    scoreg[nbase + i] = di * a + dh[i].y * di * di + bs[0];
}

// ---------------------------------------------------------------------------
// 3. Tail: per graph (64 blocks, 1024 thr): radix top-K + pooling + GAT +
//    readout + MLP. ~156 KB LDS (aliased).
// ---------------------------------------------------------------------------
#define TOFF_FADJ  0            // 19680  fadj 410x24 u16      [E..G]
#define TOFF_FCNT  19680        // 1648                        [E..G]
#define TOFF_XP    21328        // 16400  xp 410x10f           [E..F]
#define TOFF_WRED  21328        // 1920   (alias xp, dead after F) [G]
#define TOFF_GOUT  23248        // 240                         [G..H]
#define TOFF_HID   23488        // 120                         [H]
#define TOFF_HF    37728        // 98400  hf 410x60f           [F..G]
#define TOFF_BINS  37728        // 8192   (alias hf, used only in D)
#define TOFF_ALS   136128       // 4920                        [F..G]
#define TOFF_ALD   141048       // 4920                        [F..G]
#define TOFF_SK    145968       // 8192   keys                 [load..E]
#define TOFF_NEWL  154160       // 4096   newL u16             [load..G]
#define TOFF_PERML 158256       // 824                         [D..G]
#define TOFF_WSUM  159080       // 64
#define TOFF_FLAGS 159144       // 24
#define TOFF_BUFK  159168       // 256
#define TOFF_BUFI  159424       // 128
#define TARENA_SZ  159552

__global__ __launch_bounds__(1024) void k_tail(
    const float* __restrict__ scoreg, const float* __restrict__ x1g,
    const int* __restrict__ rowptrg, const unsigned short* __restrict__ csrg,
    const float* __restrict__ Wg, const float* __restrict__ a_srcw,
    const float* __restrict__ a_dstw, const float* __restrict__ bg,
    const float* __restrict__ Wf1, const float* __restrict__ bf1,
    const float* __restrict__ Wf2, const float* __restrict__ bf2,
    float* __restrict__ out)
{
    __shared__ __align__(16) char arena[TARENA_SZ];
    unsigned short* fadjL = (unsigned short*)(arena + TOFF_FADJ);
    int*            fcntL = (int*)(arena + TOFF_FCNT);
    float*          xpL   = (float*)(arena + TOFF_XP);
    float*          wred  = (float*)(arena + TOFF_WRED);
    float*          goutL = (float*)(arena + TOFF_GOUT);
    float*          hidL  = (float*)(arena + TOFF_HID);
    float*          hfL   = (float*)(arena + TOFF_HF);
    int*            bins  = (int*)(arena + TOFF_BINS);
    float*          alsL  = (float*)(arena + TOFF_ALS);
    float*          aldL  = (float*)(arena + TOFF_ALD);
    unsigned*       skL   = (unsigned*)(arena + TOFF_SK);
    unsigned short* newLs = (unsigned short*)(arena + TOFF_NEWL);
    unsigned short* permL = (unsigned short*)(arena + TOFF_PERML);
    int*            wsumL = (int*)(arena + TOFF_WSUM);
    int*            flags = (int*)(arena + TOFF_FLAGS);
    unsigned*       bufK  = (unsigned*)(arena + TOFF_BUFK);
    unsigned short* bufI  = (unsigned short*)(arena + TOFF_BUFI);
#define bselS  flags[0]
#define bneedS flags[1]
#define curS   flags[2]
#define totS   flags[3]
#define bcntS  flags[4]
#define cnt2S  flags[5]

    int g = blockIdx.x, tid = threadIdx.x, wid = tid >> 6;
    int nbase = g * NPG;

    // load keys
    for (int i = tid; i < NPG; i += 1024) {
        unsigned u = __float_as_uint(scoreg[nbase + i]);
        skL[i] = (u & 0x80000000u) ? ~u : (u | 0x80000000u);
        newLs[i] = 0xFFFFu;
        bins[i] = 0;
    }
    if (tid == 0) curS = 0;
    __syncthreads();

    // ---- Phase D: 11-bit radix level + wave-resolved boundary bucket
    for (int i = tid; i < NPG; i += 1024)
        atomicAdd(&bins[skL[i] >> 21], 1);
    __syncthreads();
    int need = KSEL;
    {
        int b2 = tid * 2;
        int v0 = bins[b2], v1 = bins[b2 + 1];
        bins[b2] = 0; bins[b2 + 1] = 0;
        int s = v0 + v1;
        int incl = wave_incl_scan(s);
        if ((tid & 63) == 63) wsumL[wid] = incl;
        __syncthreads();
        if (tid == 0) {
            int a = 0;
#pragma unroll
            for (int w = 0; w < 16; w++) { int t = wsumL[w]; wsumL[w] = a; a += t; }
            totS = a;
            cnt2S = 0;
        }
        __syncthreads();
        int base = wsumL[wid] + incl - s;
        int tot = totS;
        { int Sb = tot - base;        int Sb1 = Sb - v0; if (Sb >= need && Sb1 < need) { bselS = b2;     bneedS = need - Sb1; bcntS = v0; } }
        { int Sb = tot - (base + v0); int Sb1 = Sb - v1; if (Sb >= need && Sb1 < need) { bselS = b2 + 1; bneedS = need - Sb1; bcntS = v1; } }
        __syncthreads();
    }
    int bsel0 = bselS;
    need = bneedS;
    int bcnt = bcntS;
    int greaterCnt = KSEL - need;
    for (int i = tid; i < NPG; i += 1024) {
        unsigned k = skL[i];
        int b = (int)(k >> 21);
        if (b > bsel0) {
            int p = atomicAdd(&curS, 1);
            permL[p] = (unsigned short)i;
            newLs[i] = (unsigned short)p;
        } else if (b == bsel0 && bcnt <= 64) {
            int pos = atomicAdd(&cnt2S, 1);
            bufK[pos] = k;
            bufI[pos] = (unsigned short)i;
        }
    }
    __syncthreads();
    if (bcnt <= 64) {
        if (wid == 0) {
            unsigned k  = (tid < bcnt) ? bufK[tid] : 0u;
            unsigned ix = (tid < bcnt) ? (unsigned)bufI[tid] : 0xFFFFu;
            int rank = 0;
#pragma unroll 8
            for (int j = 0; j < 64; j++) {
                unsigned kj = __shfl(k, j, 64);
                unsigned ij = __shfl(ix, j, 64);
                if (kj > k || (kj == k && ij < ix)) rank++;
            }
            if (tid < bcnt && rank < need) {
                int p = greaterCnt + rank;
                permL[p] = (unsigned short)ix;
                newLs[ix] = (unsigned short)p;
            }
        }
    } else {
        // fallback: levels 1 (11 bits) and 2 (10 bits), then T-based assignment
        unsigned prefix = (unsigned)bsel0;
        for (int lv = 1; lv < 3; lv++) {
            for (int i = tid; i < NPG; i += 1024) {
                unsigned k = skL[i];
                bool match; unsigned bb;
                if (lv == 1) { match = ((k >> 21) == prefix); bb = (k >> 10) & 0x7FFu; }
                else         { match = ((k >> 10) == prefix); bb = k & 0x3FFu; }
                if (match) atomicAdd(&bins[bb], 1);
            }
            __syncthreads();
            int b2 = tid * 2;
            int v0 = bins[b2], v1 = bins[b2 + 1];
            bins[b2] = 0; bins[b2 + 1] = 0;
            int s = v0 + v1;
            int incl = wave_incl_scan(s);
            if ((tid & 63) == 63) wsumL[wid] = incl;
            __syncthreads();
            if (tid == 0) {
                int a = 0;
#pragma unroll
                for (int w = 0; w < 16; w++) { int t = wsumL[w]; wsumL[w] = a; a += t; }
                totS = a;
            }
            __syncthreads();
            int base = wsumL[wid] + incl - s;
            int tot = totS;
            { int Sb = tot - base;        int Sb1 = Sb - v0; if (Sb >= need && Sb1 < need) { bselS = b2;     bneedS = need - Sb1; } }
            { int Sb = tot - (base + v0); int Sb1 = Sb - v1; if (Sb >= need && Sb1 < need) { bselS = b2 + 1; bneedS = need - Sb1; } }
            __syncthreads();
            if (lv == 1) prefix = (prefix << 11) | (unsigned)bselS;
            else         prefix = (prefix << 10) | (unsigned)bselS;
            need = bneedS;
            __syncthreads();
        }
        unsigned T = prefix;
        greaterCnt = KSEL - need;
        for (int i = tid; i < NPG; i += 1024) {
            unsigned k = skL[i];
            if ((k >> 21) == (unsigned)bsel0 && k > T) {
                int p = atomicAdd(&curS, 1);
                permL[p] = (unsigned short)i;
                newLs[i] = (unsigned short)p;
            }
        }
        {
            int b2 = tid * 2;
            int lc = 0, loc2[2];
#pragma unroll
            for (int k = 0; k < 2; k++)
                if (skL[b2 + k] == T) loc2[lc++] = b2 + k;
            __syncthreads();
            int incl = wave_incl_scan(lc);
            if ((tid & 63) == 63) wsumL[wid] = incl;
            __syncthreads();
            if (tid == 0) {
                int a = 0;
#pragma unroll
                for (int w = 0; w < 16; w++) { int t = wsumL[w]; wsumL[w] = a; a += t; }
            }
            __syncthreads();
            int rank0 = wsumL[wid] + incl - lc;
            for (int j = 0; j < lc; j++) {
                int rank = rank0 + j;
                if (rank < need) {
                    int p = greaterCnt + rank;
                    permL[p] = (unsigned short)loc2[j];
                    newLs[loc2[j]] = (unsigned short)p;
                }
            }
        }
    }
    __syncthreads();

    // ---- Phase E: gated pooled features (x1 rows from global) + filtered adjacency
    for (int p = tid; p < KSEL; p += 1024) {
        int iL = permL[p];
        unsigned k = skL[iL];
        unsigned u = (k & 0x80000000u) ? (k & 0x7FFFFFFFu) : ~k;
        float tt = tanhf(__uint_as_float(u));
        const float4* xr = (const float4*)(x1g + (size_t)(nbase + iL) * RP);
        float4 q0 = xr[0], q1 = xr[1], q2 = xr[2];
        float* xp = xpL + p * 10;
        xp[0] = q0.x * tt; xp[1] = q0.y * tt; xp[2] = q0.z * tt; xp[3] = q0.w * tt;
        xp[4] = q1.x * tt; xp[5] = q1.y * tt; xp[6] = q1.z * tt; xp[7] = q1.w * tt;
        xp[8] = q2.x * tt; xp[9] = q2.y * tt;
        int p0 = rowptrg[nbase + iL], p1 = rowptrg[nbase + iL + 1];
        int c = 0;
        for (int e = p0; e < p1; e++) {
            unsigned short s2 = newLs[csrg[e]];
            if (s2 != 0xFFFFu && c < FCAP) fadjL[p * FCAP + c++] = s2;
        }
        fcntL[p] = c;
    }
    __syncthreads();

    // ---- Phase F: GAT features per (p, head); hf overwrites bins region
    for (int t = tid; t < KSEL * NH; t += 1024) {
        int p = t / NH, hh = t - p * NH;
        float xi[10];
#pragma unroll
        for (int k = 0; k < 10; k++) xi[k] = xpL[p * 10 + k];
        float v[NC];
        float as_ = 0.f, ad_ = 0.f;
#pragma unroll
        for (int c = 0; c < NC; c++) {
            int j = hh * NC + c;
            float vv = 0.f;
#pragma unroll
            for (int k = 0; k < 10; k++) vv += xi[k] * Wg[k * HC + j];
            v[c] = vv;
            as_ += vv * a_srcw[j];
            ad_ += vv * a_dstw[j];
        }
        float4* hr = (float4*)(hfL + p * HC + hh * NC);
#pragma unroll
        for (int q = 0; q < 5; q++)
            hr[q] = make_float4(v[4 * q], v[4 * q + 1], v[4 * q + 2], v[4 * q + 3]);
        alsL[p * NH + hh] = as_;
        aldL[p * NH + hh] = ad_;
    }
    __syncthreads();

    // ---- Phase G: softmax agg over filtered adjacency + butterfly readout
    {
        float res[NC];
#pragma unroll
        for (int rnd = 0; rnd < 2; rnd++) {
            int task = rnd == 0 ? tid : 1024 + tid;
            bool on = rnd == 0 || tid < KPAD;
            int hh = task >> 9, p = task & (KPAD - 1);
            if (on) {
                if (p < KSEL) {
                    float aldp = aldL[p * NH + hh];
                    float lself = leaky(alsL[p * NH + hh] + aldp);
                    float m = lself;
                    int c = fcntL[p];
                    const unsigned short* f = fadjL + p * FCAP;
                    for (int e = 0; e < c; e++)
                        m = fmaxf(m, leaky(alsL[f[e] * NH + hh] + aldp));
                    float wself = expf(lself - m), wsum = wself;
                    const float4* hp = (const float4*)(hfL + p * HC + hh * NC);
                    float4 r0 = hp[0], r1 = hp[1], r2 = hp[2], r3 = hp[3], r4 = hp[4];
                    r0.x *= wself; r0.y *= wself; r0.z *= wself; r0.w *= wself;
                    r1.x *= wself; r1.y *= wself; r1.z *= wself; r1.w *= wself;
                    r2.x *= wself; r2.y *= wself; r2.z *= wself; r2.w *= wself;
                    r3.x *= wself; r3.y *= wself; r3.z *= wself; r3.w *= wself;
                    r4.x *= wself; r4.y *= wself; r4.z *= wself; r4.w *= wself;
                    for (int e = 0; e < c; e++) {
                        int s2 = f[e];
                        float w = expf(leaky(alsL[s2 * NH + hh] + aldp) - m);
                        wsum += w;
                        const float4* hq = (const float4*)(hfL + s2 * HC + hh * NC);
                        float4 t0 = hq[0], t1 = hq[1], t2 = hq[2], t3 = hq[3], t4 = hq[4];
                        r0.x += w * t0.x; r0.y += w * t0.y; r0.z += w * t0.z; r0.w += w * t0.w;
                        r1.x += w * t1.x; r1.y += w * t1.y; r1.z += w * t1.z; r1.w += w * t1.w;
                        r2.x += w * t2.x; r2.y += w * t2.y; r2.z += w * t2.z; r2.w += w * t2.w;
                        r3.x += w * t3.x; r3.y += w * t3.y; r3.z += w * t3.z; r3.w += w * t3.w;
                        r4.x += w * t4.x; r4.y += w * t4.y; r4.z += w * t4.z; r4.w += w * t4.w;
                    }
                    float inv = 1.f / wsum;
                    res[0] = r0.x * inv;  res[1] = r0.y * inv;  res[2] = r0.z * inv;  res[3] = r0.w * inv;
                    res[4] = r1.x * inv;  res[5] = r1.y * inv;  res[6] = r1.z * inv;  res[7] = r1.w * inv;
                    res[8] = r2.x * inv;  res[9] = r2.y * inv;  res[10] = r2.z * inv; res[11] = r2.w * inv;
                    res[12] = r3.x * inv; res[13] = r3.y * inv; res[14] = r3.z * inv; res[15] = r3.w * inv;
                    res[16] = r4.x * inv; res[17] = r4.y * inv; res[18] = r4.z * inv; res[19] = r4.w * inv;
                } else {
#pragma unroll
                    for (int cc = 0; cc < NC; cc++) res[cc] = 0.f;
                }
#pragma unroll
                for (int cc = 0; cc < NC; cc++) {
                    float v = res[cc];
#pragma unroll
                    for (int d = 1; d < 64; d <<= 1) v += __shfl_xor(v, d, 64);
                    res[cc] = v;
                }
                if ((tid & 63) == 0) {
                    int slot = rnd == 0 ? hh * 8 + (wid & 7) : 16 + wid;
#pragma unroll
                    for (int cc = 0; cc < NC; cc++) wred[slot * NC + cc] = res[cc];
                }
            }
        }
    }
    __syncthreads();
    if (tid < HC) {
        int hh = tid / NC, c = tid - hh * NC;
        float a = 0.f;
#pragma unroll
        for (int w = 0; w < 8; w++) a += wred[(hh * 8 + w) * NC + c];
        goutL[tid] = a + (float)KSEL * bg[tid];
    }
    __syncthreads();

    // ---- Phase H: MLP + log_softmax
    if (tid < 30) {
        float s = bf1[tid];
#pragma unroll
        for (int k = 0; k < HC; k++) s += goutL[k] * Wf1[k * 30 + tid];
        hidL[tid] = s > 0.f ? s : 0.f;
    }
    __syncthreads();
    if (tid == 0) {
        float z[3];
#pragma unroll
        for (int j = 0; j < 3; j++) {
            float s = bf2[j];
            for (int k = 0; k < 30; k++) s += hidL[k] * Wf2[k * 3 + j];
            z[j] = s;
        }
        float m = fmaxf(z[0], fmaxf(z[1], z[2]));
        float lse = logf(expf(z[0] - m) + expf(z[1] - m) + expf(z[2] - m)) + m;
#pragma unroll
        for (int j = 0; j < 3; j++) out[g * 3 + j] = z[j] - lse;
    }
}

extern "C" void kernel_launch(void* const* d_in, const int* in_sizes, int n_in,
                              void* d_out, int out_size, void* d_ws, size_t ws_size,
                              hipStream_t stream) {
    const float* x     = (const float*)d_in[0];
    const int*   src   = (const int*)d_in[1];
    const int*   dst   = (const int*)d_in[2];
    const float* W1    = (const float*)d_in[4];
    const float* b1    = (const float*)d_in[5];
    const float* Ws    = (const float*)d_in[6];
    const float* bs    = (const float*)d_in[7];
    const float* Wg    = (const float*)d_in[8];
    const float* a_src = (const float*)d_in[9];
    const float* a_dst = (const float*)d_in[10];
    const float* bg    = (const float*)d_in[11];
    const float* Wf1   = (const float*)d_in[12];
    const float* bf1   = (const float*)d_in[13];
    const float* Wf2   = (const float*)d_in[14];
    const float* bf2   = (const float*)d_in[15];
    float* out = (float*)d_out;

    const size_t N = NTOT;
    float* ws = (float*)d_ws;
    float* x1g    = ws;                          // 12N (padded rows)
    float* hsg    = x1g + (size_t)RP * N;        // N
    float* dinvg  = hsg + N;                     // N
    float* scoreg = dinvg + N;                   // N
    int* rowptrg  = (int*)(scoreg + N);          // N+1
    unsigned short* csrg = (unsigned short*)(rowptrg + N + 2);  // NE

    k_front<<<G * CPG, 1024, 0, stream>>>(x, src, dst, W1, b1, Ws,
                                          x1g, hsg, dinvg, rowptrg, csrg);
    k_score<<<G * CPG, 512, 0, stream>>>(hsg, dinvg, rowptrg, csrg, bs, scoreg);
    k_tail<<<G, 1024, 0, stream>>>(scoreg, x1g, rowptrg, csrg, Wg, a_src, a_dst,
                                   bg, Wf1, bf1, Wf2, bf2, out);
}

// Round 15
// 142.181 us; speedup vs baseline: 1.0684x; 1.0684x over previous
//
#include <hip/hip_runtime.h>
#include <math.h>

#define G    64
#define NPG  2048
#define NTOT (G * NPG)          // 131072
#define EPG  (NPG * 8)          // 16384 edges per graph (contiguous by construction)
#define NE   (NTOT * 8)         // 1048576
#define KSEL 410
#define NH   3
#define NC   20
#define HC   60
#define FCAP 24
#define KPAD 512
#define RP   12                 // padded row: h1[0..9], dinv@10, hs@11 (48 B)

// ---- LDS arena (bytes). Lifetimes: A=csr build, B=gcn10, C=scorer, D=topk,
//      E=pool+fadj, F=gat feat, G=agg+readout, H=mlp.
#define OFF_H1P   0             // 98304  h1p 2048x12f            [A..E]
#define OFF_CSR   98304         // 32768  csr u16                 [A..E]
#define OFF_HIST  131072        // 8192   hist/bins int           [A..D]
#define OFF_RS    139264        // 8192   rs int                  [A..E]
#define OFF_SK    147456        // 8192   sk u32                  [C..E]
#define OFF_NEWL  155648        // 4096   newL u16                [C..G]
#define OFF_PERML 159744        // 824    permL u16               [D..E]
#define OFF_WSUM  160568        // 64
#define OFF_FLAGS 160632        // 16
#define ARENA_SZ  160648
// aliased into dead regions:
#define OFF_XP    0             // 16400  xp 410x10f              [E..F]  (h1p dead)
#define OFF_FADJ  16400         // 19680  fadj 410x24 u16         [E..G]
#define OFF_FCNT  36080         // 1648   fcnt int                [E..G]
#define OFF_HF    37728         // 98400  hf 410x60f              [F..G]  (h1p/csr/hist dead)
#define OFF_ALS   139264        // 4920   als                     [F..G]  (rs dead)
#define OFF_ALD   144184        // 4920   ald                     [F..G]  (sk dead)
#define OFF_WRED  149104        // 1920                           [G]
#define OFF_GOUT  151024        // 240                            [G..H]
#define OFF_HID   151264        // 120                            [H]

__device__ inline float leaky(float x) { return x >= 0.f ? x : 0.2f * x; }

__device__ inline int wave_incl_scan(int v) {
    int lane = threadIdx.x & 63;
#pragma unroll
    for (int d = 1; d < 64; d <<= 1) {
        int t = __shfl_up(v, d, 64);
        if (lane >= d) v += t;
    }
    return v;
}

__global__ __launch_bounds__(1024) void k_all(
    const float* __restrict__ x, const int* __restrict__ src, const int* __restrict__ dst,
    const float* __restrict__ W1, const float* __restrict__ b1,
    const float* __restrict__ Ws, const float* __restrict__ bs,
    const float* __restrict__ Wg, const float* __restrict__ a_srcw,
    const float* __restrict__ a_dstw, const float* __restrict__ bg,
    const float* __restrict__ Wf1, const float* __restrict__ bf1,
    const float* __restrict__ Wf2, const float* __restrict__ bf2,
    float* __restrict__ x1g, float* __restrict__ out)
{
    __shared__ __align__(16) char arena[ARENA_SZ];
    float*          h1p   = (float*)(arena + OFF_H1P);
    unsigned short* csrL  = (unsigned short*)(arena + OFF_CSR);
    int*            hist  = (int*)(arena + OFF_HIST);
    int*            rsL   = (int*)(arena + OFF_RS);
    unsigned*       skL   = (unsigned*)(arena + OFF_SK);
    unsigned short* newLs = (unsigned short*)(arena + OFF_NEWL);
    unsigned short* permL = (unsigned short*)(arena + OFF_PERML);
    int*            wsumL = (int*)(arena + OFF_WSUM);
    int*            flags = (int*)(arena + OFF_FLAGS);
    float*          xpL   = (float*)(arena + OFF_XP);
    unsigned short* fadjL = (unsigned short*)(arena + OFF_FADJ);
    int*            fcntL = (int*)(arena + OFF_FCNT);
    float*          hfL   = (float*)(arena + OFF_HF);
    float*          alsL  = (float*)(arena + OFF_ALS);
    float*          aldL  = (float*)(arena + OFF_ALD);
    float*          wred  = (float*)(arena + OFF_WRED);
    float*          goutL = (float*)(arena + OFF_GOUT);
    float*          hidL  = (float*)(arena + OFF_HID);
#define bselS  flags[0]
#define bneedS flags[1]
#define curS   flags[2]
#define totS   flags[3]

    int g = blockIdx.x, tid = threadIdx.x, wid = tid >> 6;
    int nbase = g * NPG, ebase = g * EPG;

    // ---- Phase A: zero hist; h1 -> LDS (padded rows, vector writes)
    for (int i = tid; i < NPG; i += 1024) hist[i] = 0;
    for (int i = tid; i < NPG; i += 1024) {
        float xi[5];
#pragma unroll
        for (int k = 0; k < 5; k++) xi[k] = x[(size_t)(nbase + i) * 5 + k];
        float v[10];
#pragma unroll
        for (int j = 0; j < 10; j++) {
            float s = 0.f;
#pragma unroll
            for (int k = 0; k < 5; k++) s += xi[k] * W1[k * 10 + j];
            v[j] = s;
        }
        float4* row = (float4*)(h1p + i * RP);
        row[0] = make_float4(v[0], v[1], v[2], v[3]);
        row[1] = make_float4(v[4], v[5], v[6], v[7]);
        row[2] = make_float4(v[8], v[9], 0.f, 0.f);   // slots 10/11 rewritten later
    }
    __syncthreads();
    for (int e = tid; e < EPG; e += 1024)
        atomicAdd(&hist[dst[ebase + e] - nbase], 1);
    __syncthreads();
    {   // exclusive scan (2 bins/thread, 16 wave partials); dinv -> row slot 10
        int b2 = tid * 2;
        int v0 = hist[b2], v1 = hist[b2 + 1];
        int s = v0 + v1;
        int incl = wave_incl_scan(s);
        if ((tid & 63) == 63) wsumL[wid] = incl;
        __syncthreads();
        if (tid == 0) {
            int a = 0;
#pragma unroll
            for (int w = 0; w < 16; w++) { int t = wsumL[w]; wsumL[w] = a; a += t; }
        }
        __syncthreads();
        int base = wsumL[wid] + incl - s;
        rsL[b2] = base;
        rsL[b2 + 1] = base + v0;
        h1p[b2 * RP + 10] = rsqrtf((float)v0 + 1.0f);
        h1p[(b2 + 1) * RP + 10] = rsqrtf((float)v1 + 1.0f);
        hist[b2] = 0; hist[b2 + 1] = 0;              // cursors
    }
    __syncthreads();
    for (int e = tid; e < EPG; e += 1024) {
        int ee = ebase + e;
        int sl = src[ee] - nbase;
        int dl = dst[ee] - nbase;
        int pos = rsL[dl] + atomicAdd(&hist[dl], 1);
        csrL[pos] = (unsigned short)sl;
    }
    __syncthreads();

    // ---- Phase B: GCN10 gather (vector LDS reads); x1 -> global (stride 12); hs -> slot 11
    for (int i = tid; i < NPG; i += 1024) {
        const float4* rowi = (const float4*)(h1p + i * RP);
        float4 s0 = rowi[0], s1 = rowi[1], s2 = rowi[2];
        float di = s2.z;
        float a0 = 0.f, a1 = 0.f, a2 = 0.f, a3 = 0.f, a4 = 0.f;
        float a5 = 0.f, a6 = 0.f, a7 = 0.f, a8 = 0.f, a9 = 0.f;
        int p0 = rsL[i], p1 = (i == NPG - 1) ? EPG : rsL[i + 1];
        for (int e = p0; e < p1; e++) {
            int s = csrL[e];
            const float4* rw = (const float4*)(h1p + s * RP);
            float4 r0 = rw[0], r1 = rw[1], r2 = rw[2];
            float dv = r2.z;
            a0 += r0.x * dv; a1 += r0.y * dv; a2 += r0.z * dv; a3 += r0.w * dv;
            a4 += r1.x * dv; a5 += r1.y * dv; a6 += r1.z * dv; a7 += r1.w * dv;
            a8 += r2.x * dv; a9 += r2.y * dv;
        }
        float d2 = di * di;
        float v[10];
        v[0] = a0 * di + s0.x * d2 + b1[0];
        v[1] = a1 * di + s0.y * d2 + b1[1];
        v[2] = a2 * di + s0.z * d2 + b1[2];
        v[3] = a3 * di + s0.w * d2 + b1[3];
        v[4] = a4 * di + s1.x * d2 + b1[4];
        v[5] = a5 * di + s1.y * d2 + b1[5];
        v[6] = a6 * di + s1.z * d2 + b1[6];
        v[7] = a7 * di + s1.w * d2 + b1[7];
        v[8] = a8 * di + s2.x * d2 + b1[8];
        v[9] = a9 * di + s2.y * d2 + b1[9];
        float dot = 0.f;
#pragma unroll
        for (int j = 0; j < 10; j++) dot += v[j] * Ws[j];
        float4* xr = (float4*)(x1g + (size_t)(nbase + i) * RP);
        xr[0] = make_float4(v[0], v[1], v[2], v[3]);
        xr[1] = make_float4(v[4], v[5], v[6], v[7]);
        xr[2] = make_float4(v[8], v[9], 0.f, 0.f);
        h1p[i * RP + 11] = dot;                       // hs
    }
    __syncthreads();

    // ---- Phase C: scorer gather ((dinv,hs) as one b64); keys; init topk state
    float bsv = bs[0];
    for (int i = tid; i < NPG; i += 1024) {
        float2 own = *(const float2*)(h1p + i * RP + 10);   // dinv, hs
        int p0 = rsL[i], p1 = (i == NPG - 1) ? EPG : rsL[i + 1];
        float a = 0.f;
        for (int e = p0; e < p1; e++) {
            float2 dh = *(const float2*)(h1p + csrL[e] * RP + 10);
            a += dh.x * dh.y;
        }
        float sc = own.x * a + own.y * own.x * own.x + bsv;
        unsigned u = __float_as_uint(sc);
        skL[i] = (u & 0x80000000u) ? ~u : (u | 0x80000000u);
        newLs[i] = 0xFFFFu;
        hist[i] = 0;
    }
    if (tid == 0) curS = 0;
    int need = KSEL;
    unsigned prefix = 0;
    __syncthreads();

    // ---- Phase D: 3-level radix select (11/11/10 bits)
    for (int lv = 0; lv < 3; lv++) {
        for (int i = tid; i < NPG; i += 1024) {
            unsigned k = skL[i];
            bool match; unsigned bb;
            if (lv == 0)      { match = true;                  bb = k >> 21; }
            else if (lv == 1) { match = ((k >> 21) == prefix); bb = (k >> 10) & 0x7FFu; }
            else              { match = ((k >> 10) == prefix); bb = k & 0x3FFu; }
            if (match) atomicAdd(&hist[bb], 1);
        }
        __syncthreads();
        int b2 = tid * 2;
        int v0 = hist[b2], v1 = hist[b2 + 1];
        hist[b2] = 0; hist[b2 + 1] = 0;
        int s = v0 + v1;
        int incl = wave_incl_scan(s);
        if ((tid & 63) == 63) wsumL[wid] = incl;
        __syncthreads();
        if (tid == 0) {
            int a = 0;
#pragma unroll
            for (int w = 0; w < 16; w++) { int t = wsumL[w]; wsumL[w] = a; a += t; }
            totS = a;
        }
        __syncthreads();
        int base = wsumL[wid] + incl - s;
        int tot = totS;
        { int Sb = tot - base;        int Sb1 = Sb - v0; if (Sb >= need && Sb1 < need) { bselS = b2;     bneedS = need - Sb1; } }
        { int Sb = tot - (base + v0); int Sb1 = Sb - v1; if (Sb >= need && Sb1 < need) { bselS = b2 + 1; bneedS = need - Sb1; } }
        __syncthreads();
        if (lv == 0)      prefix = (unsigned)bselS;
        else if (lv == 1) prefix = (prefix << 11) | (unsigned)bselS;
        else              prefix = (prefix << 10) | (unsigned)bselS;
        need = bneedS;
        __syncthreads();
    }
    unsigned T = prefix;              // exact K-th largest key; need = #ties to take
    int greaterCnt = KSEL - need;

    for (int i = tid; i < NPG; i += 1024) {
        if (skL[i] > T) {
            int p = atomicAdd(&curS, 1);
            permL[p] = (unsigned short)i;
            newLs[i] = (unsigned short)p;
        }
    }
    {   // ties == T: lowest indices first
        int b2 = tid * 2;
        int lc = 0, loc2[2];
#pragma unroll
        for (int k = 0; k < 2; k++)
            if (skL[b2 + k] == T) loc2[lc++] = b2 + k;
        __syncthreads();
        int incl = wave_incl_scan(lc);
        if ((tid & 63) == 63) wsumL[wid] = incl;
        __syncthreads();
        if (tid == 0) {
            int a = 0;
#pragma unroll
            for (int w = 0; w < 16; w++) { int t = wsumL[w]; wsumL[w] = a; a += t; }
        }
        __syncthreads();
        int rank0 = wsumL[wid] + incl - lc;
        for (int j = 0; j < lc; j++) {
            int rank = rank0 + j;
            if (rank < need) {
                int p = greaterCnt + rank;
                permL[p] = (unsigned short)loc2[j];
                newLs[loc2[j]] = (unsigned short)p;
            }
        }
    }
    __syncthreads();

    // ---- Phase E: gated pooled features (score from key inversion) + filtered adjacency
    for (int p = tid; p < KSEL; p += 1024) {
        int iL = permL[p];
        unsigned k = skL[iL];
        unsigned u = (k & 0x80000000u) ? (k & 0x7FFFFFFFu) : ~k;
        float tt = tanhf(__uint_as_float(u));
        const float4* xr = (const float4*)(x1g + (size_t)(nbase + iL) * RP);
        float4 q0 = xr[0], q1 = xr[1], q2 = xr[2];
        float* xp = xpL + p * 10;
        xp[0] = q0.x * tt; xp[1] = q0.y * tt; xp[2] = q0.z * tt; xp[3] = q0.w * tt;
        xp[4] = q1.x * tt; xp[5] = q1.y * tt; xp[6] = q1.z * tt; xp[7] = q1.w * tt;
        xp[8] = q2.x * tt; xp[9] = q2.y * tt;
        int p0 = rsL[iL], p1 = (iL == NPG - 1) ? EPG : rsL[iL + 1];
        int c = 0;
        for (int e = p0; e < p1; e++) {
            unsigned short s2 = newLs[csrL[e]];
            if (s2 != 0xFFFFu && c < FCAP) fadjL[p * FCAP + c++] = s2;
        }
        fcntL[p] = c;
    }
    __syncthreads();

    // ---- Phase F: GAT features per (p, head)
    for (int t = tid; t < KSEL * NH; t += 1024) {
        int p = t / NH, hh = t - p * NH;
        float xi[10];
#pragma unroll
        for (int k = 0; k < 10; k++) xi[k] = xpL[p * 10 + k];
        float v[NC];
        float as_ = 0.f, ad_ = 0.f;
#pragma unroll
        for (int c = 0; c < NC; c++) {
            int j = hh * NC + c;
            float vv = 0.f;
#pragma unroll
            for (int k = 0; k < 10; k++) vv += xi[k] * Wg[k * HC + j];
            v[c] = vv;
            as_ += vv * a_srcw[j];
            ad_ += vv * a_dstw[j];
        }
        float4* hr = (float4*)(hfL + p * HC + hh * NC);
#pragma unroll
        for (int q = 0; q < 5; q++)
            hr[q] = make_float4(v[4 * q], v[4 * q + 1], v[4 * q + 2], v[4 * q + 3]);
        alsL[p * NH + hh] = as_;
        aldL[p * NH + hh] = ad_;
    }
    __syncthreads();

    // ---- Phase G: softmax agg over filtered adjacency + butterfly readout
    {
        float res[NC];
#pragma unroll
        for (int rnd = 0; rnd < 2; rnd++) {
            int task = rnd == 0 ? tid : 1024 + tid;
            bool on = rnd == 0 || tid < KPAD;
            int hh = task >> 9, p = task & (KPAD - 1);
            if (on) {
                if (p < KSEL) {
                    float aldp = aldL[p * NH + hh];
                    float lself = leaky(alsL[p * NH + hh] + aldp);
                    float m = lself;
                    int c = fcntL[p];
                    const unsigned short* f = fadjL + p * FCAP;
                    for (int e = 0; e < c; e++)
                        m = fmaxf(m, leaky(alsL[f[e] * NH + hh] + aldp));
                    float wself = expf(lself - m), wsum = wself;
                    const float4* hp = (const float4*)(hfL + p * HC + hh * NC);
                    float4 r0 = hp[0], r1 = hp[1], r2 = hp[2], r3 = hp[3], r4 = hp[4];
                    r0.x *= wself; r0.y *= wself; r0.z *= wself; r0.w *= wself;
                    r1.x *= wself; r1.y *= wself; r1.z *= wself; r1.w *= wself;
                    r2.x *= wself; r2.y *= wself; r2.z *= wself; r2.w *= wself;
                    r3.x *= wself; r3.y *= wself; r3.z *= wself; r3.w *= wself;
                    r4.x *= wself; r4.y *= wself; r4.z *= wself; r4.w *= wself;
                    for (int e = 0; e < c; e++) {
                        int s2 = f[e];
                        float w = expf(leaky(alsL[s2 * NH + hh] + aldp) - m);
                        wsum += w;
                        const float4* hq = (const float4*)(hfL + s2 * HC + hh * NC);
                        float4 t0 = hq[0], t1 = hq[1], t2 = hq[2], t3 = hq[3], t4 = hq[4];
                        r0.x += w * t0.x; r0.y += w * t0.y; r0.z += w * t0.z; r0.w += w * t0.w;
                        r1.x += w * t1.x; r1.y += w * t1.y; r1.z += w * t1.z; r1.w += w * t1.w;
                        r2.x += w * t2.x; r2.y += w * t2.y; r2.z += w * t2.z; r2.w += w * t2.w;
                        r3.x += w * t3.x; r3.y += w * t3.y; r3.z += w * t3.z; r3.w += w * t3.w;
                        r4.x += w * t4.x; r4.y += w * t4.y; r4.z += w * t4.z; r4.w += w * t4.w;
                    }
                    float inv = 1.f / wsum;
                    res[0] = r0.x * inv;  res[1] = r0.y * inv;  res[2] = r0.z * inv;  res[3] = r0.w * inv;
                    res[4] = r1.x * inv;  res[5] = r1.y * inv;  res[6] = r1.z * inv;  res[7] = r1.w * inv;
                    res[8] = r2.x * inv;  res[9] = r2.y * inv;  res[10] = r2.z * inv; res[11] = r2.w * inv;
                    res[12] = r3.x * inv; res[13] = r3.y * inv; res[14] = r3.z * inv; res[15] = r3.w * inv;
                    res[16] = r4.x * inv; res[17] = r4.y * inv; res[18] = r4.z * inv; res[19] = r4.w * inv;
                } else {
#pragma unroll
                    for (int cc = 0; cc < NC; cc++) res[cc] = 0.f;
                }
#pragma unroll
                for (int cc = 0; cc < NC; cc++) {
                    float v = res[cc];
#pragma unroll
                    for (int d = 1; d < 64; d <<= 1) v += __shfl_xor(v, d, 64);
                    res[cc] = v;
                }
                if ((tid & 63) == 0) {
                    int slot = rnd == 0 ? hh * 8 + (wid & 7) : 16 + wid;
#pragma unroll
                    for (int cc = 0; cc < NC; cc++) wred[slot * NC + cc] = res[cc];
                }
            }
        }
    }
    __syncthreads();
    if (tid < HC) {
        int hh = tid / NC, c = tid - hh * NC;
        float a = 0.f;
#pragma unroll
        for (int w = 0; w < 8; w++) a += wred[(hh * 8 + w) * NC + c];
        goutL[tid] = a + (float)KSEL * bg[tid];
    }
    __syncthreads();

    // ---- Phase H: MLP + log_softmax
    if (tid < 30) {
        float s = bf1[tid];
#pragma unroll
        for (int k = 0; k < HC; k++) s += goutL[k] * Wf1[k * 30 + tid];
        hidL[tid] = s > 0.f ? s : 0.f;
    }
    __syncthreads();
    if (tid == 0) {
        float z[3];
#pragma unroll
        for (int j = 0; j < 3; j++) {
            float s = bf2[j];
            for (int k = 0; k < 30; k++) s += hidL[k] * Wf2[k * 3 + j];
            z[j] = s;
        }
        float m = fmaxf(z[0], fmaxf(z[1], z[2]));
        float lse = logf(expf(z[0] - m) + expf(z[1] - m) + expf(z[2] - m)) + m;
#pragma unroll
        for (int j = 0; j < 3; j++) out[g * 3 + j] = z[j] - lse;
    }
}

extern "C" void kernel_launch(void* const* d_in, const int* in_sizes, int n_in,
                              void* d_out, int out_size, void* d_ws, size_t ws_size,
                              hipStream_t stream) {
    const float* x     = (const float*)d_in[0];
    const int*   src   = (const int*)d_in[1];
    const int*   dst   = (const int*)d_in[2];
    const float* W1    = (const float*)d_in[4];
    const float* b1    = (const float*)d_in[5];
    const float* Ws    = (const float*)d_in[6];
    const float* bs    = (const float*)d_in[7];
    const float* Wg    = (const float*)d_in[8];
    const float* a_src = (const float*)d_in[9];
    const float* a_dst = (const float*)d_in[10];
    const float* bg    = (const float*)d_in[11];
    const float* Wf1   = (const float*)d_in[12];
    const float* bf1   = (const float*)d_in[13];
    const float* Wf2   = (const float*)d_in[14];
    const float* bf2   = (const float*)d_in[15];
    float* out = (float*)d_out;

    float* x1g = (float*)d_ws;    // 12 * NTOT floats (padded rows); overwritten each call

    k_all<<<G, 1024, 0, stream>>>(x, src, dst, W1, b1, Ws, bs, Wg, a_src, a_dst,
                                  bg, Wf1, bf1, Wf2, bf2, x1g, out);
}